// Round 14
// baseline (120.506 us; speedup 1.0000x reference)
//
#include <hip/hip_runtime.h>
#include <hip/hip_bf16.h>

// InfoNCE-style loss: Xn=normalize(X), Yn=normalize(Y), logits=Xn@Yn^T/0.07,
// loss = mean_i(lse_i - logits[i,i]).
// Fixed-max trick: logits <= 1/T, so lse = 1/T + ln(sum exp(logit-1/T)).
// fp8 e4m3, MX-scaled mfma_scale_f32_16x16x128_f8f6f4 (scale=1.0).
// R14: wave-independent GEMM — NO LDS, NO barriers, NO inline-asm waits.
// R8-R13 showed the cooperative-staging design pins logits at ~23us: block
// waves run in lockstep phases and the matrix pipe idles between them.
// Here each of 8192 waves owns a private 64M x 128N x 256K slice; A (64
// regs) loaded once; B streams global->VGPR straight from L2 (fragment-
// swizzled layout written by nrm makes every load base+lane*16 coalesced).
// 3 waves/SIMD (launch_bounds(256,3)) with independent phase drift.
//
// Swizzled fp8 layout (bijective, both X and Y):
//   byte (row r, col c) -> (r>>4)*4096 + (c>>7)*2048 + ((c>>4)&1)*1024
//                          + ((c>>5)&3)*256 + (r&15)*16 + (c&15)
// so fragment load (block R, kb, h) = base + R*4096 + kb*2048 + h*1024
// + lane*16 gives lane (g=lane>>4, l15): row R*16+l15, k-bytes kb*128+g*32+h*16.
//
// ws layout:
//   [0,2MB)        Xq fp8 swizzled
//   [2MB,4MB)      Yq fp8 swizzled
//   [4MB,+32KB)    diag f32[8192]
//   [4MB+32K,+32K) row_sum f32[8192]  (zeroed by nrm_kernel each call)

typedef __attribute__((ext_vector_type(2)))  float f32x2;
typedef __attribute__((ext_vector_type(4)))  float f32x4;
typedef __attribute__((ext_vector_type(4)))  int   i32x4;
typedef __attribute__((ext_vector_type(8)))  int   i32x8;

constexpr int   BROWS = 8192;
constexpr int   DDIM  = 256;
constexpr float kInvT = 14.285714285714286f;   // 1/0.07
constexpr float kC1   = 20.609929155556622f;   // log2(e)/0.07
constexpr float kLn2  = 0.6931471805599453f;
constexpr int   kSC   = 0x7F7F7F7F;            // e8m0 scale = 2^0 = 1.0

#if __has_builtin(__builtin_amdgcn_exp2f)
#define EXP2F(x) __builtin_amdgcn_exp2f(x)
#else
#define EXP2F(x) exp2f(x)
#endif
#if __has_builtin(__builtin_amdgcn_logf)
#define LOG2F(x) __builtin_amdgcn_logf(x)
#else
#define LOG2F(x) log2f(x)
#endif

// ---- f32 -> fp8 e4m3fn (RNE). Inputs here are |v| <= 1, finite. ----
static __device__ __forceinline__ unsigned f2fp8(float f) {
  unsigned u = __builtin_bit_cast(unsigned, f);
  unsigned s = (u >> 24) & 0x80u;
  float af = __builtin_fabsf(f);
  if (af < 0.015625f) {
    int q = (int)__builtin_rintf(af * 512.0f);
    return s | (unsigned)q;
  }
  unsigned au = u & 0x7FFFFFFFu;
  au += 0x7FFFFu + ((au >> 20) & 1u);
  unsigned e8 = ((au >> 23) - 127u + 7u) & 0xFu;
  unsigned m  = (au >> 20) & 7u;
  return s | (e8 << 3) | m;
}

// ------- normalize rows -> fp8 (SWIZZLED layout), exact diag, zero ws ------
__global__ __launch_bounds__(256) void nrm_kernel(
    const float* __restrict__ X, const float* __restrict__ Y,
    unsigned int* __restrict__ Xq, unsigned int* __restrict__ Yq,
    float* __restrict__ diag, float* __restrict__ row_sum)
{
  const int wave = threadIdx.x >> 6;
  const int lane = threadIdx.x & 63;
  const int row  = blockIdx.x * 4 + wave;
  const float4 x = *(const float4*)(X + (size_t)row * DDIM + lane * 4);
  const float4 y = *(const float4*)(Y + (size_t)row * DDIM + lane * 4);
  float ssx = x.x*x.x + x.y*x.y + x.z*x.z + x.w*x.w;
  float ssy = y.x*y.x + y.y*y.y + y.z*y.z + y.w*y.w;
  float dot = x.x*y.x + x.y*y.y + x.z*y.z + x.w*y.w;
  #pragma unroll
  for (int m = 1; m < 64; m <<= 1) {
    ssx += __shfl_xor(ssx, m);
    ssy += __shfl_xor(ssy, m);
    dot += __shfl_xor(dot, m);
  }
  const float invx = 1.0f / fmaxf(sqrtf(ssx), 1e-8f);
  const float invy = 1.0f / fmaxf(sqrtf(ssy), 1e-8f);
#if __has_builtin(__builtin_amdgcn_cvt_pk_fp8_f32)
  int xq = __builtin_amdgcn_cvt_pk_fp8_f32(x.x * invx, x.y * invx, 0, false);
  xq     = __builtin_amdgcn_cvt_pk_fp8_f32(x.z * invx, x.w * invx, xq, true);
  int yq = __builtin_amdgcn_cvt_pk_fp8_f32(y.x * invy, y.y * invy, 0, false);
  yq     = __builtin_amdgcn_cvt_pk_fp8_f32(y.z * invy, y.w * invy, yq, true);
#else
  int xq = (int)(f2fp8(x.x*invx) | (f2fp8(x.y*invx) << 8) |
                 (f2fp8(x.z*invx) << 16) | (f2fp8(x.w*invx) << 24));
  int yq = (int)(f2fp8(y.x*invy) | (f2fp8(y.y*invy) << 8) |
                 (f2fp8(y.z*invy) << 16) | (f2fp8(y.w*invy) << 24));
#endif
  // lane handles fp8 cols c = 4*lane .. +3 -> kb=lane>>5, h=(lane>>2)&1,
  // g=(lane>>3)&3, byte-in-chunk=(lane&3)*4. Index in u32 units:
  const int idx = (row >> 4) * 1024 + (lane >> 5) * 512 + ((lane >> 2) & 1) * 256
                + ((lane >> 3) & 3) * 64 + (row & 15) * 4 + (lane & 3);
  Xq[idx] = (unsigned)xq;
  Yq[idx] = (unsigned)yq;
  if (lane == 0) {
    diag[row] = dot * invx * invy * kInvT;
    row_sum[row] = 0.0f;
  }
}

// ---- exp of one f32x4 accumulator slice into sums (pk_fma + 4 exp) ----
static __device__ __forceinline__ void expq(const f32x4& pv, f32x2 (&sm)[2]) {
  f32x2 v0 = { pv[0], pv[1] };
  f32x2 v1 = { pv[2], pv[3] };
  v0 = v0 * kC1 + (f32x2){-kC1, -kC1};
  v1 = v1 * kC1 + (f32x2){-kC1, -kC1};
  sm[0] += (f32x2){ EXP2F(v0.x), EXP2F(v0.y) };
  sm[1] += (f32x2){ EXP2F(v1.x), EXP2F(v1.y) };
}

// ---------------- main: wave-independent exp-sum of logits -----------------
// 2048 blocks x 256 thr = 8192 waves; wave (mg, ng) computes X-rows
// [mg*64,+64) x Y-rows [ng*128,+128) x K=256 entirely from registers.
// Per n-frag (16 Y-rows): 4 coalesced dwordx4 loads, 8 MFMAs, 16 exps.
// Fully unrolled; compiler software-pipelines loads with counted vmcnt.
// XCD map: xcd owns ng-slice [xcd*8,+8) x all mg -> Y slice 256KB L2-hot.
__global__ __launch_bounds__(256, 3) void logits_kernel(
    const unsigned char* __restrict__ Xq,
    const unsigned char* __restrict__ Yq,
    float* __restrict__ row_sum)
{
  const int lane = threadIdx.x & 63;
  const int wv   = threadIdx.x >> 6;
  const int bid  = blockIdx.x;
  const int xcd  = bid & 7;
  const int widx = (bid >> 3) * 4 + wv;        // 0..1023 within XCD
  const int mg   = widx & 127;                  // M group (64 rows)
  const int ng   = xcd * 8 + (widx >> 7);       // N group (128 Y-rows)
  const int l15  = lane & 15;
  const int g    = lane >> 4;

  const char* Xb = (const char*)Xq + (size_t)mg * 16384 + lane * 16;
  const char* Yb = (const char*)Yq + (size_t)ng * 32768 + lane * 16;

  // A fragments: 4 m-frags x 2 kb, 64 VGPRs, loaded once.
  i32x8 a[4][2];
  #pragma unroll
  for (int m = 0; m < 4; ++m)
    #pragma unroll
    for (int kb = 0; kb < 2; ++kb) {
      const i32x4 lo = *(const i32x4*)(Xb + m * 4096 + kb * 2048);
      const i32x4 hi = *(const i32x4*)(Xb + m * 4096 + kb * 2048 + 1024);
      a[m][kb] = __builtin_shufflevector(lo, hi, 0, 1, 2, 3, 4, 5, 6, 7);
    }

  f32x2 sums2[4][2];
  #pragma unroll
  for (int m = 0; m < 4; ++m) {
    sums2[m][0] = (f32x2){0.f, 0.f};
    sums2[m][1] = (f32x2){0.f, 0.f};
  }

  #pragma unroll
  for (int nf = 0; nf < 8; ++nf) {
    f32x4 acc[4];
    __builtin_amdgcn_s_setprio(1);
    #pragma unroll
    for (int kb = 0; kb < 2; ++kb) {
      const i32x4 lo = *(const i32x4*)(Yb + nf * 4096 + kb * 2048);
      const i32x4 hi = *(const i32x4*)(Yb + nf * 4096 + kb * 2048 + 1024);
      const i32x8 b = __builtin_shufflevector(lo, hi, 0, 1, 2, 3, 4, 5, 6, 7);
      #pragma unroll
      for (int m = 0; m < 4; ++m) {
        acc[m] = (kb == 0)
          ? __builtin_amdgcn_mfma_scale_f32_16x16x128_f8f6f4(
                a[m][0], b, (f32x4){0.f, 0.f, 0.f, 0.f}, 0, 0, 0, kSC, 0, kSC)
          : __builtin_amdgcn_mfma_scale_f32_16x16x128_f8f6f4(
                a[m][1], b, acc[m], 0, 0, 0, kSC, 0, kSC);
      }
    }
    __builtin_amdgcn_s_setprio(0);
    #pragma unroll
    for (int m = 0; m < 4; ++m)
      expq(acc[m], sums2[m]);
  }

  // reduce across the 16 column-lanes; one atomic per row per wave.
  // C/D mapping (16x16 family, R1-verified): col=l15, row = g*4 + reg.
  #pragma unroll
  for (int m = 0; m < 4; ++m)
    #pragma unroll
    for (int h = 0; h < 2; ++h)
      #pragma unroll
      for (int r2 = 0; r2 < 2; ++r2) {
        float s = (r2 == 0) ? sums2[m][h].x : sums2[m][h].y;
        s += __shfl_xor(s, 1);
        s += __shfl_xor(s, 2);
        s += __shfl_xor(s, 4);
        s += __shfl_xor(s, 8);
        if (l15 == 0)
          atomicAdd(row_sum + mg * 64 + m * 16 + g * 4 + h * 2 + r2, s);
      }
}

// ---------------- loss: single-kernel reduction (separate launch) ----------
__global__ __launch_bounds__(1024) void loss_kernel(
    const float* __restrict__ row_sum, const float* __restrict__ diag,
    float* __restrict__ out)
{
  const int t = threadIdx.x;
  double acc = 0.0;
  #pragma unroll
  for (int h = 0; h < 2; ++h) {
    const int i = h * 4096 + t * 4;
    const float4 s = *(const float4*)(row_sum + i);
    const float4 d = *(const float4*)(diag + i);
    acc += (double)(kInvT + LOG2F(s.x) * kLn2 - d.x);
    acc += (double)(kInvT + LOG2F(s.y) * kLn2 - d.y);
    acc += (double)(kInvT + LOG2F(s.z) * kLn2 - d.z);
    acc += (double)(kInvT + LOG2F(s.w) * kLn2 - d.w);
  }
  #pragma unroll
  for (int m = 1; m < 64; m <<= 1) acc += __shfl_xor(acc, m);
  __shared__ double red[16];
  if ((t & 63) == 0) red[t >> 6] = acc;
  __syncthreads();
  if (t == 0) {
    double tot = 0.0;
    #pragma unroll
    for (int w = 0; w < 16; ++w) tot += red[w];
    out[0] = (float)(tot / (double)BROWS);
  }
}

extern "C" void kernel_launch(void* const* d_in, const int* in_sizes, int n_in,
                              void* d_out, int out_size, void* d_ws, size_t ws_size,
                              hipStream_t stream) {
  (void)in_sizes; (void)n_in; (void)out_size; (void)ws_size;
  const float* X = (const float*)d_in[0];
  const float* Y = (const float*)d_in[1];
  char* w = (char*)d_ws;
  unsigned int* Xq = (unsigned int*)(w);
  unsigned int* Yq = (unsigned int*)(w + (2u << 20));
  float* diag    = (float*)(w + (4u << 20));
  float* row_sum = (float*)(w + (4u << 20) + (32u << 10));

  nrm_kernel<<<BROWS / 4, 256, 0, stream>>>(X, Y, Xq, Yq, diag, row_sum);
  logits_kernel<<<2048, 256, 0, stream>>>((const unsigned char*)Xq,
                                          (const unsigned char*)Yq, row_sum);
  loss_kernel<<<1, 1024, 0, stream>>>(row_sum, diag, (float*)d_out);
}

// Round 15
// 34.798 us; speedup vs baseline: 3.4630x; 3.4630x over previous
//
#include <hip/hip_runtime.h>
#include <hip/hip_bf16.h>

// InfoNCE-style loss: Xn=normalize(X), Yn=normalize(Y), logits=Xn@Yn^T/0.07,
// loss = mean_i(lse_i - logits[i,i]).
// Fixed-max trick: logits <= 1/T, so lse = 1/T + ln(sum exp(logit-1/T)).
// fp8 e4m3 inputs, MX-scaled mfma_scale_f32_16x16x128_f8f6f4, scale=1.0.
// R15: EXACT restoration of the R9 champion (34.7us verified; VGPR 96, 0
// bank conflicts, no spill). Every structural departure regressed:
//   R10 forced-4-wave spill (144us), R11 SGB misfire (59us), R12 fence
//   storm (93us), R13 4-block overhead (41us), R14 LDS-free spill (120us).
// Design invariants this kernel embodies (each counter-verified):
//  - MX-fp8 16x16x128, 4-reg acc tuples, A in 64 regs -> no spill at 96 VGPR
//  - shared 8KB B-tiles, 4-deep ring, width-16 global_load_lds
//  - 4-bit XOR slot swizzle -> SQ_LDS_BANK_CONFLICT = 0
//  - counted vmcnt(4)+s_barrier per tile (loads in flight across barriers)
//  - T15 double-acc: prev tile's exps hide under current tile's MFMAs
//  - separate tiny loss kernel (device-fence fusion = L2-invalidate storm)
//
// ws layout:
//   [0,2MB)        Xq fp8 [8192][256]
//   [2MB,4MB)      Yq fp8 [8192][256]
//   [4MB,+32KB)    diag f32[8192]
//   [4MB+32K,+32K) row_sum f32[8192]  (zeroed by nrm_kernel each call)

typedef __attribute__((ext_vector_type(2)))  float f32x2;
typedef __attribute__((ext_vector_type(4)))  float f32x4;
typedef __attribute__((ext_vector_type(4)))  int   i32x4;
typedef __attribute__((ext_vector_type(8)))  int   i32x8;

#define AS1(p) ((const __attribute__((address_space(1))) void*)(uintptr_t)(p))
#define AS3(p) ((__attribute__((address_space(3))) void*)(uintptr_t)(p))

constexpr int   BROWS = 8192;
constexpr int   DDIM  = 256;
constexpr float kInvT = 14.285714285714286f;   // 1/0.07
constexpr float kC1   = 20.609929155556622f;   // log2(e)/0.07
constexpr float kLn2  = 0.6931471805599453f;
constexpr int   kSC   = 0x7F7F7F7F;            // e8m0 scale bytes = 2^0 = 1.0

#if __has_builtin(__builtin_amdgcn_exp2f)
#define EXP2F(x) __builtin_amdgcn_exp2f(x)
#else
#define EXP2F(x) exp2f(x)
#endif
#if __has_builtin(__builtin_amdgcn_logf)
#define LOG2F(x) __builtin_amdgcn_logf(x)
#else
#define LOG2F(x) log2f(x)
#endif

// ---- f32 -> fp8 e4m3fn (RNE). Inputs here are |v| <= 1, finite. ----
static __device__ __forceinline__ unsigned f2fp8(float f) {
  unsigned u = __builtin_bit_cast(unsigned, f);
  unsigned s = (u >> 24) & 0x80u;
  float af = __builtin_fabsf(f);
  if (af < 0.015625f) {                    // below min normal 2^-6: denorm steps 2^-9
    int q = (int)__builtin_rintf(af * 512.0f);   // 0..8 (8 rolls into min normal)
    return s | (unsigned)q;
  }
  unsigned au = u & 0x7FFFFFFFu;
  au += 0x7FFFFu + ((au >> 20) & 1u);      // RNE on 3-bit mantissa
  unsigned e8 = ((au >> 23) - 127u + 7u) & 0xFu;
  unsigned m  = (au >> 20) & 7u;
  return s | (e8 << 3) | m;
}

// ---------------- normalize rows -> fp8, exact fp32 diagonal, zero row_sum --
__global__ __launch_bounds__(256) void nrm_kernel(
    const float* __restrict__ X, const float* __restrict__ Y,
    unsigned int* __restrict__ Xq, unsigned int* __restrict__ Yq,
    float* __restrict__ diag, float* __restrict__ row_sum)
{
  const int wave = threadIdx.x >> 6;
  const int lane = threadIdx.x & 63;
  const int row  = blockIdx.x * 4 + wave;
  const float4 x = *(const float4*)(X + (size_t)row * DDIM + lane * 4);
  const float4 y = *(const float4*)(Y + (size_t)row * DDIM + lane * 4);
  float ssx = x.x*x.x + x.y*x.y + x.z*x.z + x.w*x.w;
  float ssy = y.x*y.x + y.y*y.y + y.z*y.z + y.w*y.w;
  float dot = x.x*y.x + x.y*y.y + x.z*y.z + x.w*y.w;
  #pragma unroll
  for (int m = 1; m < 64; m <<= 1) {
    ssx += __shfl_xor(ssx, m);
    ssy += __shfl_xor(ssy, m);
    dot += __shfl_xor(dot, m);
  }
  const float invx = 1.0f / fmaxf(sqrtf(ssx), 1e-8f);
  const float invy = 1.0f / fmaxf(sqrtf(ssy), 1e-8f);
#if __has_builtin(__builtin_amdgcn_cvt_pk_fp8_f32)
  int xq = __builtin_amdgcn_cvt_pk_fp8_f32(x.x * invx, x.y * invx, 0, false);
  xq     = __builtin_amdgcn_cvt_pk_fp8_f32(x.z * invx, x.w * invx, xq, true);
  int yq = __builtin_amdgcn_cvt_pk_fp8_f32(y.x * invy, y.y * invy, 0, false);
  yq     = __builtin_amdgcn_cvt_pk_fp8_f32(y.z * invy, y.w * invy, yq, true);
#else
  int xq = (int)(f2fp8(x.x*invx) | (f2fp8(x.y*invx) << 8) |
                 (f2fp8(x.z*invx) << 16) | (f2fp8(x.w*invx) << 24));
  int yq = (int)(f2fp8(y.x*invy) | (f2fp8(y.y*invy) << 8) |
                 (f2fp8(y.z*invy) << 16) | (f2fp8(y.w*invy) << 24));
#endif
  Xq[row * 64 + lane] = (unsigned)xq;
  Yq[row * 64 + lane] = (unsigned)yq;
  if (lane == 0) {
    diag[row] = dot * invx * invy * kInvT;
    row_sum[row] = 0.0f;
  }
}

// -------- exp-flush of one m-slice of the PREVIOUS tile's accumulators ------
static __device__ __forceinline__ void expflush(f32x4 (&pm)[2], f32x2 (&sm)[2]) {
  #pragma unroll
  for (int n = 0; n < 2; ++n) {
    f32x2 v0 = { pm[n][0], pm[n][1] };
    f32x2 v1 = { pm[n][2], pm[n][3] };
    v0 = v0 * kC1 + (f32x2){-kC1, -kC1};   // v_pk_fma_f32
    v1 = v1 * kC1 + (f32x2){-kC1, -kC1};
    sm[0] += (f32x2){ EXP2F(v0.x), EXP2F(v0.y) };
    sm[1] += (f32x2){ EXP2F(v1.x), EXP2F(v1.y) };
  }
}

// -------- one B-tile (32 Y-rows x 256B fp8): 16 MX-MFMAs + T15 exp overlap --
// Reads use XOR-composed addresses: addr = bb[n] ^ {0,16,128,144} (4-bit
// slot swizzle puts kb in the XOR key, so kb=1 is ^128 not +128).
static __device__ __forceinline__ void tile_step(
    const char* __restrict__ tb, const int (&bb)[2], const i32x8 (&a)[4][2],
    f32x4 (&cur)[4][2], f32x4 (&prev)[4][2], f32x2 (&sums2)[4][2])
{
  i32x8 b[2];
  __builtin_amdgcn_s_setprio(1);
  #pragma unroll
  for (int n = 0; n < 2; ++n) {
    const i32x4 lo = *(const i32x4*)(tb + (bb[n]));
    const i32x4 hi = *(const i32x4*)(tb + (bb[n] ^ 16));
    b[n] = __builtin_shufflevector(lo, hi, 0, 1, 2, 3, 4, 5, 6, 7);
  }
  #pragma unroll
  for (int m = 0; m < 4; ++m) {
    cur[m][0] = __builtin_amdgcn_mfma_scale_f32_16x16x128_f8f6f4(
        a[m][0], b[0], (f32x4){0.f, 0.f, 0.f, 0.f}, 0, 0, 0, kSC, 0, kSC);
    cur[m][1] = __builtin_amdgcn_mfma_scale_f32_16x16x128_f8f6f4(
        a[m][0], b[1], (f32x4){0.f, 0.f, 0.f, 0.f}, 0, 0, 0, kSC, 0, kSC);
  }
  __builtin_amdgcn_s_setprio(0);
  expflush(prev[0], sums2[0]);
  expflush(prev[1], sums2[1]);
  __builtin_amdgcn_s_setprio(1);
  #pragma unroll
  for (int n = 0; n < 2; ++n) {
    const i32x4 lo = *(const i32x4*)(tb + (bb[n] ^ 128));
    const i32x4 hi = *(const i32x4*)(tb + (bb[n] ^ 144));
    b[n] = __builtin_shufflevector(lo, hi, 0, 1, 2, 3, 4, 5, 6, 7);
  }
  #pragma unroll
  for (int m = 0; m < 4; ++m) {
    cur[m][0] = __builtin_amdgcn_mfma_scale_f32_16x16x128_f8f6f4(
        a[m][1], b[0], cur[m][0], 0, 0, 0, kSC, 0, kSC);
    cur[m][1] = __builtin_amdgcn_mfma_scale_f32_16x16x128_f8f6f4(
        a[m][1], b[1], cur[m][1], 0, 0, 0, kSC, 0, kSC);
  }
  __builtin_amdgcn_s_setprio(0);
  expflush(prev[2], sums2[2]);
  expflush(prev[3], sums2[3]);
}

// ---------------- main: exp-sum of logits over all columns ----------------
// 512 blocks x 256 thr (4 waves). Wave owns 64 X-rows = 4 m-frags of 16; A
// (fp8) in regs (64). Shared B tiles: 32 Y-rows x 256B (8KB), 4-deep ring
// (32KB LDS), all 4 waves co-stage (2 x 1KB global_load_lds each).
// LDS swizzle: byte (r,c) stored at r*256 + (((c>>4) ^ (r&15))<<4 | (c&15))
// -> every ds_read_b128 is 2 lanes/slot = conflict-free (0 measured).
// Schedule per tile t (counted-vmcnt pattern, never drain in-loop):
//   s_waitcnt vmcnt(4)   ; my 2 ops for tile t retired (t+1..t+3 in flight)
//   s_barrier            ; all waves' portions of t landed; t-1 fully read
//   stage(t+3)           ; overwrites buf[(t-1)&3], safe after barrier
//   tile_step(buf[t&3])
// Epilogue waits: t=14 -> vmcnt(2), t=15 -> vmcnt(0).
__global__ __launch_bounds__(256, 2) void logits_kernel(
    const unsigned char* __restrict__ Xq,
    const unsigned char* __restrict__ Yq,
    float* __restrict__ row_sum)
{
  __shared__ char lds[4 * 8192];
  const int tid  = threadIdx.x;
  const int lane = tid & 63;
  const int wave = tid >> 6;
  const int l15  = lane & 15;
  const int g    = lane >> 4;      // 0..3: k-group / C-row group

  // XCD-aware bijective map: xcd=bid&7 owns 16 panels x 4 splits
  const int bid  = blockIdx.x;
  const int xcd  = bid & 7;
  const int idx  = bid >> 3;                        // 0..63
  const int panel = (xcd >> 2) * 16 + (idx & 15);   // 0..31
  const int split = (xcd & 3) * 4 + (idx >> 4);     // 0..15

  const int rowbase = panel * 256 + wave * 64;
  const char* Xb = (const char*)Xq;
  const char* Yb = (const char*)Yq + (size_t)split * (512 * 256);

  // A fragments (16x16x128 fp8): lane holds row (rowbase+16m+l15),
  // k-bytes [kb*128 + g*32, +32) -> i32x8 (32B, aligned).
  i32x8 a[4][2];
  #pragma unroll
  for (int m = 0; m < 4; ++m) {
    const char* rp = Xb + (size_t)(rowbase + m * 16 + l15) * 256 + g * 32;
    a[m][0] = *(const i32x8*)(rp);
    a[m][1] = *(const i32x8*)(rp + 128);
  }

  f32x2 sums2[4][2];
  #pragma unroll
  for (int m = 0; m < 4; ++m) {
    sums2[m][0] = (f32x2){0.f, 0.f};
    sums2[m][1] = (f32x2){0.f, 0.f};
  }

  // B read bases: row r = n*16+l15, slot s16 = kb*8 + 2g + h, swizzled
  // slot' = s16 ^ l15  ->  base (kb=0,h=0): r*256 + ((2g ^ l15)<<4);
  // other three reads are base ^ 16 (h), ^128 (kb), ^144 (both).
  int bb[2];
  #pragma unroll
  for (int n = 0; n < 2; ++n)
    bb[n] = (n * 16 + l15) * 256 + (((2 * g) ^ l15) << 4);

  // Co-staged: wave stages 2KB of the 8KB tile (2 x width-16 ops).
  auto stage = [&](int t, int buf) {
    const char* Yt = Yb + (size_t)t * 8192;
    char* db = lds + buf * 8192;
    #pragma unroll
    for (int s = 0; s < 2; ++s) {
      const int portion = (s * 4 + wave) * 1024;
      const int L = portion + lane * 16;
      const int src = (L & ~255) | ((L & 255) ^ (((L >> 8) & 15) << 4));
      __builtin_amdgcn_global_load_lds(AS1(Yt + src), AS3(db + portion), 16, 0, 0);
    }
  };

  // T15 double-acc: accA = cur of even tiles, accB = cur of odd tiles.
  // accB starts at -inf so tile 0's "prev" exp contributes exactly 0.
  f32x4 accA[4][2], accB[4][2];
  #pragma unroll
  for (int m = 0; m < 4; ++m)
    #pragma unroll
    for (int n = 0; n < 2; ++n) {
      accA[m][n] = (f32x4){0.f, 0.f, 0.f, 0.f};
      const float ni = -__builtin_inff();
      accB[m][n] = (f32x4){ni, ni, ni, ni};
    }

  stage(0, 0);
  stage(1, 1);
  stage(2, 2);
  #pragma unroll 1
  for (int p = 0; p < 8; ++p) {
    const int t = 2 * p;
    // even tile t
    if (p < 7) asm volatile("s_waitcnt vmcnt(4)" ::: "memory");
    else       asm volatile("s_waitcnt vmcnt(2)" ::: "memory");
    __builtin_amdgcn_s_barrier();
    if (t + 3 < 16) stage(t + 3, (t + 3) & 3);
    tile_step(lds + (t & 3) * 8192, bb, a, accA, accB, sums2);
    // odd tile t+1
    if (p < 7) asm volatile("s_waitcnt vmcnt(4)" ::: "memory");
    else       asm volatile("s_waitcnt vmcnt(0)" ::: "memory");
    __builtin_amdgcn_s_barrier();
    if (t + 4 < 16) stage(t + 4, (t + 4) & 3);
    tile_step(lds + ((t + 1) & 3) * 8192, bb, a, accB, accA, sums2);
  }
  // flush tile 15 (its results live in accB)
  #pragma unroll
  for (int m = 0; m < 4; ++m)
    expflush(accB[m], sums2[m]);

  // reduce across the 16 column-lanes; one atomic per row per split.
  // C/D mapping (16x16 family, R1-verified): col=l15, row = g*4 + reg.
  #pragma unroll
  for (int m = 0; m < 4; ++m)
    #pragma unroll
    for (int h = 0; h < 2; ++h)
      #pragma unroll
      for (int r2 = 0; r2 < 2; ++r2) {
        float s = (r2 == 0) ? sums2[m][h].x : sums2[m][h].y;
        s += __shfl_xor(s, 1);
        s += __shfl_xor(s, 2);
        s += __shfl_xor(s, 4);
        s += __shfl_xor(s, 8);
        if (l15 == 0)
          atomicAdd(row_sum + rowbase + m * 16 + g * 4 + h * 2 + r2, s);
      }
}

// ---------------- loss: single-kernel reduction (separate launch) ----------
__global__ __launch_bounds__(1024) void loss_kernel(
    const float* __restrict__ row_sum, const float* __restrict__ diag,
    float* __restrict__ out)
{
  const int t = threadIdx.x;
  double acc = 0.0;
  #pragma unroll
  for (int h = 0; h < 2; ++h) {
    const int i = h * 4096 + t * 4;
    const float4 s = *(const float4*)(row_sum + i);
    const float4 d = *(const float4*)(diag + i);
    acc += (double)(kInvT + LOG2F(s.x) * kLn2 - d.x);
    acc += (double)(kInvT + LOG2F(s.y) * kLn2 - d.y);
    acc += (double)(kInvT + LOG2F(s.z) * kLn2 - d.z);
    acc += (double)(kInvT + LOG2F(s.w) * kLn2 - d.w);
  }
  #pragma unroll
  for (int m = 1; m < 64; m <<= 1) acc += __shfl_xor(acc, m);
  __shared__ double red[16];
  if ((t & 63) == 0) red[t >> 6] = acc;
  __syncthreads();
  if (t == 0) {
    double tot = 0.0;
    #pragma unroll
    for (int w = 0; w < 16; ++w) tot += red[w];
    out[0] = (float)(tot / (double)BROWS);
  }
}

extern "C" void kernel_launch(void* const* d_in, const int* in_sizes, int n_in,
                              void* d_out, int out_size, void* d_ws, size_t ws_size,
                              hipStream_t stream) {
  (void)in_sizes; (void)n_in; (void)out_size; (void)ws_size;
  const float* X = (const float*)d_in[0];
  const float* Y = (const float*)d_in[1];
  char* w = (char*)d_ws;
  unsigned int* Xq = (unsigned int*)(w);
  unsigned int* Yq = (unsigned int*)(w + (2u << 20));
  float* diag    = (float*)(w + (4u << 20));
  float* row_sum = (float*)(w + (4u << 20) + (32u << 10));

  nrm_kernel<<<BROWS / 4, 256, 0, stream>>>(X, Y, Xq, Yq, diag, row_sum);
  logits_kernel<<<512, 256, 0, stream>>>((const unsigned char*)Xq,
                                         (const unsigned char*)Yq, row_sum);
  loss_kernel<<<1, 1024, 0, stream>>>(row_sum, diag, (float*)d_out);
}